// Round 9
// baseline (259.878 us; speedup 1.0000x reference)
//
#include <hip/hip_runtime.h>

#define EPS_BN 1e-5f
#define NBLK 512

typedef __attribute__((ext_vector_type(8))) short short8v;
typedef __attribute__((ext_vector_type(4))) float f32x4;

__device__ inline unsigned short f2bf(float f) {
    union { float f; unsigned u; } v; v.f = f;
    unsigned r = v.u + 0x7fffu + ((v.u >> 16) & 1u);
    return (unsigned short)(r >> 16);
}

// Software grid barrier: monotonic counter, per-phase target.
// Release: agent-scope fence (writes back XCD L2); acquire: fence after poll.
__device__ inline void gridbar(unsigned* cnt, unsigned target) {
    __syncthreads();
    if (threadIdx.x == 0) {
        __threadfence();   // release: prior global writes visible device-wide
        __hip_atomic_fetch_add(cnt, 1u, __ATOMIC_RELEASE, __HIP_MEMORY_SCOPE_AGENT);
        while (__hip_atomic_load(cnt, __ATOMIC_ACQUIRE, __HIP_MEMORY_SCOPE_AGENT) < target)
            __builtin_amdgcn_s_sleep(8);
        __threadfence();   // acquire: invalidate stale L1/L2 before phase reads
    }
    __syncthreads();
}

// ---------------- phase bodies (verbatim R8 logic, indices from vb) ----------

__device__ inline void comp_body(
    const float* __restrict__ X, const unsigned short* __restrict__ Wcb,
    const float* __restrict__ g1, const float* __restrict__ b1,
    const float* __restrict__ m1, const float* __restrict__ v1,
    unsigned short* __restrict__ tpad, int vb, int tid)
{
    const int wseg = vb % 3;
    const int h    = (vb / 3) % 48;
    const int b    = vb / 144;
    const int wave = tid >> 6;
    const int l    = tid & 63;
    const int lr   = l & 15;
    const int lk   = l >> 4;
    const int w0   = wseg * 16;

    f32x4 acc = {0.f,0.f,0.f,0.f};
    const float* xb = X + (size_t)b * 589824 + h * 48 + w0 + lr;
    const unsigned short* wb = Wcb + (wave * 16 + lr) * 256;

    #pragma unroll
    for (int s = 0; s < 8; ++s) {
        const int ci0 = s * 32 + lk * 8;
        short8v a;
        #pragma unroll
        for (int j = 0; j < 8; ++j)
            a[j] = (short)f2bf(xb[(size_t)(ci0 + j) * 2304]);
        const short8v f = *(const short8v*)(wb + ci0);
        acc = __builtin_amdgcn_mfma_f32_16x16x32_bf16(a, f, acc, 0, 0, 0);
    }

    const int oc = wave * 16 + lr;
    const float sc = g1[oc] * rsqrtf(v1[oc] + EPS_BN);
    const float sh = b1[oc] - m1[oc] * sc;
    unsigned short* tp = tpad + ((b*50 + h + 1)*50 + 1)*64 + oc;
    #pragma unroll
    for (int r = 0; r < 4; ++r) {
        float v = fmaf(acc[r], sc, sh);
        float t = v / (1.f + __expf(-v));          // SiLU
        tp[(w0 + lk*4 + r)*64] = f2bf(t);
    }
}

__device__ inline void enc_body(
    const unsigned short* __restrict__ tpad, const unsigned short* __restrict__ Web,
    const float* __restrict__ g2, const float* __restrict__ b2,
    const float* __restrict__ m2, const float* __restrict__ v2,
    float* __restrict__ Wl, int vb, int tid, float* elds)
{
    const int wseg = vb % 3;
    const int h    = (vb / 3) % 48;
    const int b    = vb / 144;
    const int wave = tid >> 6;
    const int l    = tid & 63;
    const int lr   = l & 15;
    const int lk   = l >> 4;
    const int w0   = wseg * 16;
    const int nt0  = wave * 2, nt1 = wave * 2 + 1;

    f32x4 acc0 = {0.f,0.f,0.f,0.f};
    f32x4 acc1 = {0.f,0.f,0.f,0.f};

    const unsigned short* tb = tpad + (b*50 + h)*50*64;
    const unsigned short* wb0 = Web + (nt0*16 + lr)*576;
    const unsigned short* wb1 = Web + (nt1*16 + lr)*576;

    #pragma unroll 6
    for (int s = 0; s < 18; ++s) {
        const int kk = s >> 1;
        const int ky = (kk * 11) >> 5;
        const int kx = kk - ky * 3;
        const int cio = ((s & 1) << 5) + lk * 8;
        const short8v a  = *(const short8v*)(tb + (ky*50 + w0 + kx + lr)*64 + cio);
        const short8v f0 = *(const short8v*)(wb0 + kk*64 + cio);
        const short8v f1 = *(const short8v*)(wb1 + kk*64 + cio);
        acc0 = __builtin_amdgcn_mfma_f32_16x16x32_bf16(a, f0, acc0, 0, 0, 0);
        acc1 = __builtin_amdgcn_mfma_f32_16x16x32_bf16(a, f1, acc1, 0, 0, 0);
    }

    #pragma unroll
    for (int t = 0; t < 2; ++t) {
        const int nt = t ? nt1 : nt0;
        if (nt >= 7) continue;
        const int ch = nt*16 + lr;
        float sc = 0.f, sh = 0.f;
        if (ch < 100) {
            sc = g2[ch] * rsqrtf(v2[ch] + EPS_BN);
            sh = b2[ch] - m2[ch]*sc;
        }
        const f32x4 acc = t ? acc1 : acc0;
        #pragma unroll
        for (int r = 0; r < 4; ++r)
            elds[(lk*4 + r)*116 + ch] = fmaf(acc[r], sc, sh);
    }
    __syncthreads();

    if (tid < 64) {
        const int px = tid >> 2;
        const int s  = tid & 3;
        const float* ep = &elds[px*116 + s];
        float ev[25];
        float mx = -1e30f;
        #pragma unroll
        for (int k = 0; k < 25; ++k) { ev[k] = ep[4*k]; mx = fmaxf(mx, ev[k]); }
        float sum = 0.f;
        #pragma unroll
        for (int k = 0; k < 25; ++k) { ev[k] = __expf(ev[k] - mx); sum += ev[k]; }
        const float rs = 1.f / sum;
        float* wp = Wl + ((b*48 + h)*48 + w0 + px)*112 + s*28;
        #pragma unroll
        for (int k4 = 0; k4 < 6; ++k4) {
            float4 o = { ev[k4*4+0]*rs, ev[k4*4+1]*rs, ev[k4*4+2]*rs, ev[k4*4+3]*rs };
            *(float4*)(wp + k4*4) = o;
        }
        wp[24] = ev[24]*rs;
    }
}

__device__ inline void carafe_body(
    const float* __restrict__ X, const float* __restrict__ Wl,
    float* __restrict__ out, int vb, int tid, float* xl)
{
    const int cg = vb % 16;
    const int h  = (vb / 16) % 48;
    const int b  = vb / 768;

    for (int idx = tid; idx < 960; idx += 256) {
        const int ci  = idx / 60;
        const int rem = idx - ci * 60;
        const int r   = rem / 12;
        const int q   = rem - r * 12;
        const int hh  = h - 2 + r;
        float4 v = {0.f,0.f,0.f,0.f};
        if ((unsigned)hh < 48u)
            v = *(const float4*)&X[(size_t)(b*256 + cg*16 + ci)*2304 + hh*48 + q*4];
        float* base = &xl[(((ci>>2)*5 + r)*53 + 2 + q*4)*4 + (ci&3)];
        base[0]  = v.x;
        base[4]  = v.y;
        base[8]  = v.z;
        base[12] = v.w;
    }
    for (int idx = tid; idx < 320; idx += 256) {
        const int ci  = idx / 20;
        const int rem = idx - ci * 20;
        const int r   = rem / 4;
        const int e   = rem & 3;
        const int cp  = (e < 2) ? e : 48 + e;
        xl[(((ci>>2)*5 + r)*53 + cp)*4 + (ci&3)] = 0.f;
    }
    __syncthreads();

    const int c4g = tid & 3;
    const int w   = tid >> 2;
    if (w < 48) {
        float4 xv[25];
        #pragma unroll
        for (int r = 0; r < 5; ++r)
            #pragma unroll
            for (int dx = 0; dx < 5; ++dx)
                xv[r*5 + dx] = *(const float4*)&xl[((c4g*5 + r)*53 + (w + dx))*4];
        const float* wb = &Wl[(size_t)((b*48 + h)*48 + w)*112];
        #pragma unroll
        for (int s = 0; s < 4; ++s) {
            float ax=0.f, ay=0.f, az=0.f, aw=0.f;
            #pragma unroll
            for (int k4 = 0; k4 < 6; ++k4) {
                const float4 wv = *(const float4*)&wb[s*28 + k4*4];
                const float4 p0 = xv[k4*4+0], p1 = xv[k4*4+1], p2 = xv[k4*4+2], p3 = xv[k4*4+3];
                ax = fmaf(wv.x,p0.x,fmaf(wv.y,p1.x,fmaf(wv.z,p2.x,fmaf(wv.w,p3.x,ax))));
                ay = fmaf(wv.x,p0.y,fmaf(wv.y,p1.y,fmaf(wv.z,p2.y,fmaf(wv.w,p3.y,ay))));
                az = fmaf(wv.x,p0.z,fmaf(wv.y,p1.z,fmaf(wv.z,p2.z,fmaf(wv.w,p3.z,az))));
                aw = fmaf(wv.x,p0.w,fmaf(wv.y,p1.w,fmaf(wv.z,p2.w,fmaf(wv.w,p3.w,aw))));
            }
            const float wk = wb[s*28 + 24];
            const float4 pl = xv[24];
            ax = fmaf(wk,pl.x,ax); ay = fmaf(wk,pl.y,ay);
            az = fmaf(wk,pl.z,az); aw = fmaf(wk,pl.w,aw);
            const int y = 2*h + (s>>1);
            const int x = 2*w + (s&1);
            float* ob = &out[((size_t)(b*256 + cg*16 + c4g*4)*96 + y)*96 + x];
            ob[0]     = ax;
            ob[9216]  = ay;
            ob[18432] = az;
            ob[27648] = aw;
        }
    }
}

// ---------------------------------------------------------------------------
// MEGA kernel: P0 prep -> bar -> P1 comp -> bar -> P2 enc -> bar -> P3 carafe x3
// grid 512 blocks x 256 thr, __launch_bounds__(256,2) guarantees co-residency.
// ---------------------------------------------------------------------------
__global__ __launch_bounds__(256, 2) void mega(
    const float* __restrict__ X,
    const float* __restrict__ w_comp, const float* __restrict__ w_enc,
    const float* __restrict__ g1, const float* __restrict__ b1,
    const float* __restrict__ m1, const float* __restrict__ v1,
    const float* __restrict__ g2, const float* __restrict__ b2,
    const float* __restrict__ m2, const float* __restrict__ v2,
    unsigned short* __restrict__ tpad, unsigned short* __restrict__ Web,
    unsigned short* __restrict__ Wcb, float* __restrict__ Wl,
    float* __restrict__ out, unsigned* __restrict__ bar)
{
    __shared__ __align__(16) char smbuf[16960];
    const int rb  = blockIdx.x;
    const int tid = threadIdx.x;
    const int gtid = rb * 256 + tid;

    // ---- P0: prep (zero tpad, build Web, Wcb)
    {
        if (gtid < 40000) ((uint4*)tpad)[gtid] = (uint4){0u,0u,0u,0u};
        if (gtid < 73728) {
            int ch = gtid / 576;
            int r  = gtid - ch * 576;
            int kk = r >> 6;
            int ci = r & 63;
            float v = (ch < 100) ? w_enc[ch * 576 + ci * 9 + kk] : 0.f;
            Web[gtid] = f2bf(v);
        }
        if (gtid < 16384) Wcb[gtid] = f2bf(w_comp[gtid]);
    }
    gridbar(bar, 1u * NBLK);

    // ---- P1: comp (288 virtual blocks)
    if (rb < 288)
        comp_body(X, Wcb, g1, b1, m1, v1, tpad, rb, tid);
    gridbar(bar, 2u * NBLK);

    // ---- P2: enc (288 virtual blocks)
    if (rb < 288)
        enc_body(tpad, Web, g2, b2, m2, v2, Wl, rb, tid, (float*)smbuf);
    gridbar(bar, 3u * NBLK);

    // ---- P3: carafe (1536 virtual blocks, 3 per real block)
    #pragma unroll 1
    for (int i = 0; i < 3; ++i) {
        if (i) __syncthreads();
        carafe_body(X, Wl, out, rb * 3 + i, tid, (float*)smbuf);
    }
}

extern "C" void kernel_launch(void* const* d_in, const int* in_sizes, int n_in,
                              void* d_out, int out_size, void* d_ws, size_t ws_size,
                              hipStream_t stream)
{
    (void)in_sizes; (void)n_in; (void)out_size; (void)ws_size;
    const float* X      = (const float*)d_in[0];
    const float* w_comp = (const float*)d_in[1];
    const float* g1     = (const float*)d_in[2];
    const float* b1     = (const float*)d_in[3];
    const float* m1     = (const float*)d_in[4];
    const float* v1     = (const float*)d_in[5];
    const float* w_enc  = (const float*)d_in[6];
    const float* g2     = (const float*)d_in[7];
    const float* b2     = (const float*)d_in[8];
    const float* m2     = (const float*)d_in[9];
    const float* v2     = (const float*)d_in[10];
    float* out = (float*)d_out;

    char* ws = (char*)d_ws;
    unsigned short* tpad = (unsigned short*)(ws + 0);        // 640000 B
    unsigned short* Web  = (unsigned short*)(ws + 640000);   // 147456 B
    unsigned short* Wcb  = (unsigned short*)(ws + 787456);   // 32768 B
    float*          Wl   = (float*)(ws + 820224);            // 2064384 B
    unsigned*       bar  = (unsigned*)(ws + 2884608);        // 4 B

    hipMemsetAsync(bar, 0, 4, stream);
    mega<<<NBLK, 256, 0, stream>>>(X, w_comp, w_enc, g1, b1, m1, v1,
                                   g2, b2, m2, v2,
                                   tpad, Web, Wcb, Wl, out, bar);
}

// Round 10
// 138.249 us; speedup vs baseline: 1.8798x; 1.8798x over previous
//
#include <hip/hip_runtime.h>

#define EPS_BN 1e-5f
#define NBLK 512

typedef __attribute__((ext_vector_type(8))) short short8v;
typedef __attribute__((ext_vector_type(4))) float f32x4;

__device__ inline unsigned short f2bf(float f) {
    union { float f; unsigned u; } v; v.f = f;
    unsigned r = v.u + 0x7fffu + ((v.u >> 16) & 1u);
    return (unsigned short)(r >> 16);
}

// Software grid barrier.
// RELEASE add: one L2 writeback, publishes this block's phase writes.
// Spin: RELAXED atomic loads (device-coherent, NO cache invalidate) + s_sleep.
// Exit: one ACQUIRE RMW (single invalidate so next phase sees remote data).
__device__ inline void gridbar(unsigned* cnt, unsigned target) {
    __syncthreads();
    if (threadIdx.x == 0) {
        __hip_atomic_fetch_add(cnt, 1u, __ATOMIC_RELEASE, __HIP_MEMORY_SCOPE_AGENT);
        unsigned v;
        do {
            v = __hip_atomic_load(cnt, __ATOMIC_RELAXED, __HIP_MEMORY_SCOPE_AGENT);
            if (v < target) __builtin_amdgcn_s_sleep(16);
        } while (v < target);
        __hip_atomic_fetch_add(cnt, 0u, __ATOMIC_ACQUIRE, __HIP_MEMORY_SCOPE_AGENT);
    }
    __syncthreads();
}

// ---------------- phase bodies (verbatim R8 logic, indices from vb) ----------

__device__ inline void comp_body(
    const float* __restrict__ X, const unsigned short* __restrict__ Wcb,
    const float* __restrict__ g1, const float* __restrict__ b1,
    const float* __restrict__ m1, const float* __restrict__ v1,
    unsigned short* __restrict__ tpad, int vb, int tid)
{
    const int wseg = vb % 3;
    const int h    = (vb / 3) % 48;
    const int b    = vb / 144;
    const int wave = tid >> 6;
    const int l    = tid & 63;
    const int lr   = l & 15;
    const int lk   = l >> 4;
    const int w0   = wseg * 16;

    f32x4 acc = {0.f,0.f,0.f,0.f};
    const float* xb = X + (size_t)b * 589824 + h * 48 + w0 + lr;
    const unsigned short* wb = Wcb + (wave * 16 + lr) * 256;

    #pragma unroll
    for (int s = 0; s < 8; ++s) {
        const int ci0 = s * 32 + lk * 8;
        short8v a;
        #pragma unroll
        for (int j = 0; j < 8; ++j)
            a[j] = (short)f2bf(xb[(size_t)(ci0 + j) * 2304]);
        const short8v f = *(const short8v*)(wb + ci0);
        acc = __builtin_amdgcn_mfma_f32_16x16x32_bf16(a, f, acc, 0, 0, 0);
    }

    const int oc = wave * 16 + lr;
    const float sc = g1[oc] * rsqrtf(v1[oc] + EPS_BN);
    const float sh = b1[oc] - m1[oc] * sc;
    unsigned short* tp = tpad + ((b*50 + h + 1)*50 + 1)*64 + oc;
    #pragma unroll
    for (int r = 0; r < 4; ++r) {
        float v = fmaf(acc[r], sc, sh);
        float t = v / (1.f + __expf(-v));          // SiLU
        tp[(w0 + lk*4 + r)*64] = f2bf(t);
    }
}

__device__ inline void enc_body(
    const unsigned short* __restrict__ tpad, const unsigned short* __restrict__ Web,
    const float* __restrict__ g2, const float* __restrict__ b2,
    const float* __restrict__ m2, const float* __restrict__ v2,
    float* __restrict__ Wl, int vb, int tid, float* elds)
{
    const int wseg = vb % 3;
    const int h    = (vb / 3) % 48;
    const int b    = vb / 144;
    const int wave = tid >> 6;
    const int l    = tid & 63;
    const int lr   = l & 15;
    const int lk   = l >> 4;
    const int w0   = wseg * 16;
    const int nt0  = wave * 2, nt1 = wave * 2 + 1;

    f32x4 acc0 = {0.f,0.f,0.f,0.f};
    f32x4 acc1 = {0.f,0.f,0.f,0.f};

    const unsigned short* tb = tpad + (b*50 + h)*50*64;
    const unsigned short* wb0 = Web + (nt0*16 + lr)*576;
    const unsigned short* wb1 = Web + (nt1*16 + lr)*576;

    #pragma unroll 6
    for (int s = 0; s < 18; ++s) {
        const int kk = s >> 1;
        const int ky = (kk * 11) >> 5;
        const int kx = kk - ky * 3;
        const int cio = ((s & 1) << 5) + lk * 8;
        const short8v a  = *(const short8v*)(tb + (ky*50 + w0 + kx + lr)*64 + cio);
        const short8v f0 = *(const short8v*)(wb0 + kk*64 + cio);
        const short8v f1 = *(const short8v*)(wb1 + kk*64 + cio);
        acc0 = __builtin_amdgcn_mfma_f32_16x16x32_bf16(a, f0, acc0, 0, 0, 0);
        acc1 = __builtin_amdgcn_mfma_f32_16x16x32_bf16(a, f1, acc1, 0, 0, 0);
    }

    #pragma unroll
    for (int t = 0; t < 2; ++t) {
        const int nt = t ? nt1 : nt0;
        if (nt >= 7) continue;
        const int ch = nt*16 + lr;
        float sc = 0.f, sh = 0.f;
        if (ch < 100) {
            sc = g2[ch] * rsqrtf(v2[ch] + EPS_BN);
            sh = b2[ch] - m2[ch]*sc;
        }
        const f32x4 acc = t ? acc1 : acc0;
        #pragma unroll
        for (int r = 0; r < 4; ++r)
            elds[(lk*4 + r)*116 + ch] = fmaf(acc[r], sc, sh);
    }
    __syncthreads();

    if (tid < 64) {
        const int px = tid >> 2;
        const int s  = tid & 3;
        const float* ep = &elds[px*116 + s];
        float ev[25];
        float mx = -1e30f;
        #pragma unroll
        for (int k = 0; k < 25; ++k) { ev[k] = ep[4*k]; mx = fmaxf(mx, ev[k]); }
        float sum = 0.f;
        #pragma unroll
        for (int k = 0; k < 25; ++k) { ev[k] = __expf(ev[k] - mx); sum += ev[k]; }
        const float rs = 1.f / sum;
        float* wp = Wl + ((b*48 + h)*48 + w0 + px)*112 + s*28;
        #pragma unroll
        for (int k4 = 0; k4 < 6; ++k4) {
            float4 o = { ev[k4*4+0]*rs, ev[k4*4+1]*rs, ev[k4*4+2]*rs, ev[k4*4+3]*rs };
            *(float4*)(wp + k4*4) = o;
        }
        wp[24] = ev[24]*rs;
    }
}

__device__ inline void carafe_body(
    const float* __restrict__ X, const float* __restrict__ Wl,
    float* __restrict__ out, int vb, int tid, float* xl)
{
    const int cg = vb % 16;
    const int h  = (vb / 16) % 48;
    const int b  = vb / 768;

    for (int idx = tid; idx < 960; idx += 256) {
        const int ci  = idx / 60;
        const int rem = idx - ci * 60;
        const int r   = rem / 12;
        const int q   = rem - r * 12;
        const int hh  = h - 2 + r;
        float4 v = {0.f,0.f,0.f,0.f};
        if ((unsigned)hh < 48u)
            v = *(const float4*)&X[(size_t)(b*256 + cg*16 + ci)*2304 + hh*48 + q*4];
        float* base = &xl[(((ci>>2)*5 + r)*53 + 2 + q*4)*4 + (ci&3)];
        base[0]  = v.x;
        base[4]  = v.y;
        base[8]  = v.z;
        base[12] = v.w;
    }
    for (int idx = tid; idx < 320; idx += 256) {
        const int ci  = idx / 20;
        const int rem = idx - ci * 20;
        const int r   = rem / 4;
        const int e   = rem & 3;
        const int cp  = (e < 2) ? e : 48 + e;
        xl[(((ci>>2)*5 + r)*53 + cp)*4 + (ci&3)] = 0.f;
    }
    __syncthreads();

    const int c4g = tid & 3;
    const int w   = tid >> 2;
    if (w < 48) {
        float4 xv[25];
        #pragma unroll
        for (int r = 0; r < 5; ++r)
            #pragma unroll
            for (int dx = 0; dx < 5; ++dx)
                xv[r*5 + dx] = *(const float4*)&xl[((c4g*5 + r)*53 + (w + dx))*4];
        const float* wb = &Wl[(size_t)((b*48 + h)*48 + w)*112];
        #pragma unroll
        for (int s = 0; s < 4; ++s) {
            float ax=0.f, ay=0.f, az=0.f, aw=0.f;
            #pragma unroll
            for (int k4 = 0; k4 < 6; ++k4) {
                const float4 wv = *(const float4*)&wb[s*28 + k4*4];
                const float4 p0 = xv[k4*4+0], p1 = xv[k4*4+1], p2 = xv[k4*4+2], p3 = xv[k4*4+3];
                ax = fmaf(wv.x,p0.x,fmaf(wv.y,p1.x,fmaf(wv.z,p2.x,fmaf(wv.w,p3.x,ax))));
                ay = fmaf(wv.x,p0.y,fmaf(wv.y,p1.y,fmaf(wv.z,p2.y,fmaf(wv.w,p3.y,ay))));
                az = fmaf(wv.x,p0.z,fmaf(wv.y,p1.z,fmaf(wv.z,p2.z,fmaf(wv.w,p3.z,az))));
                aw = fmaf(wv.x,p0.w,fmaf(wv.y,p1.w,fmaf(wv.z,p2.w,fmaf(wv.w,p3.w,aw))));
            }
            const float wk = wb[s*28 + 24];
            const float4 pl = xv[24];
            ax = fmaf(wk,pl.x,ax); ay = fmaf(wk,pl.y,ay);
            az = fmaf(wk,pl.z,az); aw = fmaf(wk,pl.w,aw);
            const int y = 2*h + (s>>1);
            const int x = 2*w + (s&1);
            float* ob = &out[((size_t)(b*256 + cg*16 + c4g*4)*96 + y)*96 + x];
            ob[0]     = ax;
            ob[9216]  = ay;
            ob[18432] = az;
            ob[27648] = aw;
        }
    }
}

// ---------------------------------------------------------------------------
// MEGA kernel: P0 prep -> bar -> P1 comp -> bar -> P2 enc -> bar -> P3 carafe x3
// grid 512 blocks x 256 thr, __launch_bounds__(256,2) guarantees co-residency.
// ---------------------------------------------------------------------------
__global__ __launch_bounds__(256, 2) void mega(
    const float* __restrict__ X,
    const float* __restrict__ w_comp, const float* __restrict__ w_enc,
    const float* __restrict__ g1, const float* __restrict__ b1,
    const float* __restrict__ m1, const float* __restrict__ v1,
    const float* __restrict__ g2, const float* __restrict__ b2,
    const float* __restrict__ m2, const float* __restrict__ v2,
    unsigned short* __restrict__ tpad, unsigned short* __restrict__ Web,
    unsigned short* __restrict__ Wcb, float* __restrict__ Wl,
    float* __restrict__ out, unsigned* __restrict__ bar)
{
    __shared__ __align__(16) char smbuf[16960];
    const int rb  = blockIdx.x;
    const int tid = threadIdx.x;
    const int gtid = rb * 256 + tid;

    // ---- P0: prep (zero tpad, build Web, Wcb)
    {
        if (gtid < 40000) ((uint4*)tpad)[gtid] = (uint4){0u,0u,0u,0u};
        if (gtid < 73728) {
            int ch = gtid / 576;
            int r  = gtid - ch * 576;
            int kk = r >> 6;
            int ci = r & 63;
            float v = (ch < 100) ? w_enc[ch * 576 + ci * 9 + kk] : 0.f;
            Web[gtid] = f2bf(v);
        }
        if (gtid < 16384) Wcb[gtid] = f2bf(w_comp[gtid]);
    }
    gridbar(bar, 1u * NBLK);

    // ---- P1: comp (288 virtual blocks)
    if (rb < 288)
        comp_body(X, Wcb, g1, b1, m1, v1, tpad, rb, tid);
    gridbar(bar, 2u * NBLK);

    // ---- P2: enc (288 virtual blocks)
    if (rb < 288)
        enc_body(tpad, Web, g2, b2, m2, v2, Wl, rb, tid, (float*)smbuf);
    gridbar(bar, 3u * NBLK);

    // ---- P3: carafe (1536 virtual blocks, 3 per real block)
    #pragma unroll 1
    for (int i = 0; i < 3; ++i) {
        if (i) __syncthreads();
        carafe_body(X, Wl, out, rb * 3 + i, tid, (float*)smbuf);
    }
}

extern "C" void kernel_launch(void* const* d_in, const int* in_sizes, int n_in,
                              void* d_out, int out_size, void* d_ws, size_t ws_size,
                              hipStream_t stream)
{
    (void)in_sizes; (void)n_in; (void)out_size; (void)ws_size;
    const float* X      = (const float*)d_in[0];
    const float* w_comp = (const float*)d_in[1];
    const float* g1     = (const float*)d_in[2];
    const float* b1     = (const float*)d_in[3];
    const float* m1     = (const float*)d_in[4];
    const float* v1     = (const float*)d_in[5];
    const float* w_enc  = (const float*)d_in[6];
    const float* g2     = (const float*)d_in[7];
    const float* b2     = (const float*)d_in[8];
    const float* m2     = (const float*)d_in[9];
    const float* v2     = (const float*)d_in[10];
    float* out = (float*)d_out;

    char* ws = (char*)d_ws;
    unsigned short* tpad = (unsigned short*)(ws + 0);        // 640000 B
    unsigned short* Web  = (unsigned short*)(ws + 640000);   // 147456 B
    unsigned short* Wcb  = (unsigned short*)(ws + 787456);   // 32768 B
    float*          Wl   = (float*)(ws + 820224);            // 2064384 B
    unsigned*       bar  = (unsigned*)(ws + 2884608);        // 4 B

    hipMemsetAsync(bar, 0, 4, stream);
    mega<<<NBLK, 256, 0, stream>>>(X, w_comp, w_enc, g1, b1, m1, v1,
                                   g2, b2, m2, v2,
                                   tpad, Web, Wcb, Wl, out, bar);
}

// Round 11
// 87.339 us; speedup vs baseline: 2.9755x; 1.5829x over previous
//
#include <hip/hip_runtime.h>

#define EPS_BN 1e-5f

typedef __attribute__((ext_vector_type(8))) short short8v;
typedef __attribute__((ext_vector_type(4))) float f32x4;

__device__ inline unsigned short f2bf(float f) {
    union { float f; unsigned u; } v; v.f = f;
    unsigned r = v.u + 0x7fffu + ((v.u >> 16) & 1u);
    return (unsigned short)(r >> 16);
}

// ---------------------------------------------------------------------------
// Kernel A v3: 1x1 conv (256->64) MFMA (B-operand converted on the fly from
// fp32 w_comp) + BN + SiLU -> tpad interior.  Side jobs (independent of the
// MFMA result, consumed only by the NEXT kernel): build Web (1 elem/thread,
// 288*256 == 73728 exactly) and zero tpad's border halo (25088 elems).
// grid (wseg=3, h=48, b=2) = 288 blocks, block 256.
// ---------------------------------------------------------------------------
__global__ __launch_bounds__(256) void comp_mfma(
    const float* __restrict__ X, const float* __restrict__ w_comp,
    const float* __restrict__ w_enc,
    const float* __restrict__ g1, const float* __restrict__ b1,
    const float* __restrict__ m1, const float* __restrict__ v1,
    unsigned short* __restrict__ tpad, unsigned short* __restrict__ Web)
{
    const int wseg = blockIdx.x;
    const int h = blockIdx.y;
    const int b = blockIdx.z;
    const int tid  = threadIdx.x;

    // ---- side job 1: Web[ch][kk*64+ci] bf16 from w_enc[ch][ci][kk]
    {
        const int i = ((wseg + 3*(h + 48*b)) << 8) | tid;   // 0..73727, each once
        const int ch = i / 576;
        const int r  = i - ch * 576;
        const int kk = r >> 6;
        const int ci = r & 63;
        const float v = (ch < 100) ? w_enc[ch * 576 + ci * 9 + kk] : 0.f;
        Web[i] = f2bf(v);
        // ---- side job 2: zero tpad border (196 px * 64 ch * 2 b)
        if (i < 25088) {
            const int bb  = i / 12544;
            const int rem = i - bb * 12544;
            const int p   = rem >> 6;
            const int chn = rem & 63;
            int rr, cc;
            if (p < 50)       { rr = 0;       cc = p;       }
            else if (p < 100) { rr = 49;      cc = p - 50;  }
            else if (p < 148) { rr = p - 99;  cc = 0;       }
            else              { rr = p - 147; cc = 49;      }
            tpad[((bb*50 + rr)*50 + cc)*64 + chn] = 0;
        }
    }

    // ---- main: comp MFMA
    const int wave = tid >> 6;
    const int l    = tid & 63;
    const int lr   = l & 15;
    const int lk   = l >> 4;
    const int w0   = wseg * 16;

    f32x4 acc = {0.f,0.f,0.f,0.f};
    const float* xb = X + (size_t)b * 589824 + h * 48 + w0 + lr;
    const float* wb = w_comp + (wave * 16 + lr) * 256;

    #pragma unroll
    for (int s = 0; s < 8; ++s) {
        const int ci0 = s * 32 + lk * 8;
        short8v a, f;
        const float4 wv0 = *(const float4*)(wb + ci0);
        const float4 wv1 = *(const float4*)(wb + ci0 + 4);
        f[0] = (short)f2bf(wv0.x); f[1] = (short)f2bf(wv0.y);
        f[2] = (short)f2bf(wv0.z); f[3] = (short)f2bf(wv0.w);
        f[4] = (short)f2bf(wv1.x); f[5] = (short)f2bf(wv1.y);
        f[6] = (short)f2bf(wv1.z); f[7] = (short)f2bf(wv1.w);
        #pragma unroll
        for (int j = 0; j < 8; ++j)
            a[j] = (short)f2bf(xb[(size_t)(ci0 + j) * 2304]);
        acc = __builtin_amdgcn_mfma_f32_16x16x32_bf16(a, f, acc, 0, 0, 0);
    }

    const int oc = wave * 16 + lr;
    const float sc = g1[oc] * rsqrtf(v1[oc] + EPS_BN);
    const float sh = b1[oc] - m1[oc] * sc;
    unsigned short* tp = tpad + ((b*50 + h + 1)*50 + 1)*64 + oc;
    #pragma unroll
    for (int r = 0; r < 4; ++r) {
        float v = fmaf(acc[r], sc, sh);
        float t = v / (1.f + __expf(-v));          // SiLU
        tp[(w0 + lk*4 + r)*64] = f2bf(t);
    }
}

// ---------------------------------------------------------------------------
// Kernel B (R4/R8): 3x3 conv (64->100) MFMA + BN + fused softmax -> Wl fp32.
// grid (wseg=3, h=48, b=2), block 256 (4 waves).
// ---------------------------------------------------------------------------
__global__ __launch_bounds__(256) void enc_sm(
    const unsigned short* __restrict__ tpad, const unsigned short* __restrict__ Web,
    const float* __restrict__ g2, const float* __restrict__ b2,
    const float* __restrict__ m2, const float* __restrict__ v2,
    float* __restrict__ Wl)
{
    const int wseg = blockIdx.x;
    const int h = blockIdx.y;
    const int b = blockIdx.z;
    const int tid  = threadIdx.x;
    const int wave = tid >> 6;
    const int l    = tid & 63;
    const int lr   = l & 15;
    const int lk   = l >> 4;
    const int w0   = wseg * 16;
    const int nt0  = wave * 2, nt1 = wave * 2 + 1;
    __shared__ float elds[16 * 116];

    f32x4 acc0 = {0.f,0.f,0.f,0.f};
    f32x4 acc1 = {0.f,0.f,0.f,0.f};

    const unsigned short* tb = tpad + (b*50 + h)*50*64;
    const unsigned short* wb0 = Web + (nt0*16 + lr)*576;
    const unsigned short* wb1 = Web + (nt1*16 + lr)*576;

    #pragma unroll 6
    for (int s = 0; s < 18; ++s) {
        const int kk = s >> 1;
        const int ky = (kk * 11) >> 5;
        const int kx = kk - ky * 3;
        const int cio = ((s & 1) << 5) + lk * 8;
        const short8v a  = *(const short8v*)(tb + (ky*50 + w0 + kx + lr)*64 + cio);
        const short8v f0 = *(const short8v*)(wb0 + kk*64 + cio);
        const short8v f1 = *(const short8v*)(wb1 + kk*64 + cio);
        acc0 = __builtin_amdgcn_mfma_f32_16x16x32_bf16(a, f0, acc0, 0, 0, 0);
        acc1 = __builtin_amdgcn_mfma_f32_16x16x32_bf16(a, f1, acc1, 0, 0, 0);
    }

    #pragma unroll
    for (int t = 0; t < 2; ++t) {
        const int nt = t ? nt1 : nt0;
        if (nt >= 7) continue;
        const int ch = nt*16 + lr;
        float sc = 0.f, sh = 0.f;
        if (ch < 100) {
            sc = g2[ch] * rsqrtf(v2[ch] + EPS_BN);
            sh = b2[ch] - m2[ch]*sc;
        }
        const f32x4 acc = t ? acc1 : acc0;
        #pragma unroll
        for (int r = 0; r < 4; ++r)
            elds[(lk*4 + r)*116 + ch] = fmaf(acc[r], sc, sh);
    }
    __syncthreads();

    if (tid < 64) {
        const int px = tid >> 2;
        const int s  = tid & 3;
        const float* ep = &elds[px*116 + s];
        float ev[25];
        float mx = -1e30f;
        #pragma unroll
        for (int k = 0; k < 25; ++k) { ev[k] = ep[4*k]; mx = fmaxf(mx, ev[k]); }
        float sum = 0.f;
        #pragma unroll
        for (int k = 0; k < 25; ++k) { ev[k] = __expf(ev[k] - mx); sum += ev[k]; }
        const float rs = 1.f / sum;
        float* wp = Wl + ((b*48 + h)*48 + w0 + px)*112 + s*28;
        #pragma unroll
        for (int k4 = 0; k4 < 6; ++k4) {
            float4 o = { ev[k4*4+0]*rs, ev[k4*4+1]*rs, ev[k4*4+2]*rs, ev[k4*4+3]*rs };
            *(float4*)(wp + k4*4) = o;
        }
        wp[24] = ev[24]*rs;
    }
}

// ---------------------------------------------------------------------------
// Kernel C v7: reassembly with NO LDS, NO barrier.  Lane owns 1 channel x 12
// consecutive w.  Weight addresses are wave-uniform (wg = tid>>6) -> broadcast
// L2 loads.  X window (5 rows x 16 cols) in 80 VGPRs, static indexing (jw
// fully unrolled).  Outputs stored as float2 pairs (thread-contiguous x).
// grid (cgrp=4, h=48, b=2) = 384 blocks, block 256 (4 waves).
// ---------------------------------------------------------------------------
__global__ __launch_bounds__(256) void carafe_v7(
    const float* __restrict__ X, const float* __restrict__ Wl,
    float* __restrict__ out)
{
    const int cgrp = blockIdx.x;
    const int h    = blockIdx.y;
    const int b    = blockIdx.z;
    const int tid  = threadIdx.x;
    const int c    = cgrp*64 + (tid & 63);
    const int wg   = tid >> 6;          // wave-uniform
    const int w0   = wg * 12;

    // X window: rows h-2..h+2, cols w0-2..w0+13 (zero-padded)
    float xw[5][16];
    const float* xc = X + (size_t)(b*256 + c) * 2304;
    #pragma unroll
    for (int r = 0; r < 5; ++r) {
        const int hh = h - 2 + r;
        if ((unsigned)hh < 48u) {
            const float* xr = xc + hh*48;
            #pragma unroll
            for (int j = 0; j < 16; ++j) {
                const int cw = w0 - 2 + j;
                xw[r][j] = ((unsigned)cw < 48u) ? xr[cw] : 0.f;
            }
        } else {
            #pragma unroll
            for (int j = 0; j < 16; ++j) xw[r][j] = 0.f;
        }
    }

    const float* wbase = Wl + (size_t)((b*48 + h)*48 + w0) * 112;
    float* obase = out + ((size_t)(b*256 + c)*96 + 2*h)*96;

    #pragma unroll
    for (int jw = 0; jw < 12; ++jw) {
        const float* wb = wbase + jw*112;
        float a[4];
        #pragma unroll
        for (int s = 0; s < 4; ++s) {
            float acc = 0.f;
            #pragma unroll
            for (int k4 = 0; k4 < 6; ++k4) {
                const float4 wv = *(const float4*)&wb[s*28 + k4*4];
                #pragma unroll
                for (int j = 0; j < 4; ++j) {
                    const int k  = k4*4 + j;
                    const int ky = k / 5;
                    const int kx = k - ky*5;
                    const float wj = (j==0)?wv.x:(j==1)?wv.y:(j==2)?wv.z:wv.w;
                    acc = fmaf(wj, xw[ky][jw + kx], acc);
                }
            }
            acc = fmaf(wb[s*28 + 24], xw[4][jw + 4], acc);
            a[s] = acc;
        }
        const int x0 = 2*(w0 + jw);
        *(float2*)(obase + x0)      = make_float2(a[0], a[1]);
        *(float2*)(obase + 96 + x0) = make_float2(a[2], a[3]);
    }
}

extern "C" void kernel_launch(void* const* d_in, const int* in_sizes, int n_in,
                              void* d_out, int out_size, void* d_ws, size_t ws_size,
                              hipStream_t stream)
{
    (void)in_sizes; (void)n_in; (void)out_size; (void)ws_size;
    const float* X      = (const float*)d_in[0];
    const float* w_comp = (const float*)d_in[1];
    const float* g1     = (const float*)d_in[2];
    const float* b1     = (const float*)d_in[3];
    const float* m1     = (const float*)d_in[4];
    const float* v1     = (const float*)d_in[5];
    const float* w_enc  = (const float*)d_in[6];
    const float* g2     = (const float*)d_in[7];
    const float* b2     = (const float*)d_in[8];
    const float* m2     = (const float*)d_in[9];
    const float* v2     = (const float*)d_in[10];
    float* out = (float*)d_out;

    char* ws = (char*)d_ws;
    unsigned short* tpad = (unsigned short*)(ws + 0);        // 640000 B
    unsigned short* Web  = (unsigned short*)(ws + 640000);   // 147456 B
    float*          Wl   = (float*)(ws + 787456);            // 2064384 B

    dim3 gA(3, 48, 2);
    comp_mfma<<<gA, 256, 0, stream>>>(X, w_comp, w_enc, g1, b1, m1, v1, tpad, Web);
    dim3 gB(3, 48, 2);
    enc_sm<<<gB, 256, 0, stream>>>(tpad, Web, g2, b2, m2, v2, Wl);
    dim3 gC(4, 48, 2);
    carafe_v7<<<gC, 256, 0, stream>>>(X, Wl, out);
}

// Round 12
// 43.431 us; speedup vs baseline: 5.9837x; 2.0110x over previous
//
#include <hip/hip_runtime.h>

#define EPS_BN 1e-5f

typedef __attribute__((ext_vector_type(8))) short short8v;
typedef __attribute__((ext_vector_type(4))) float f32x4;

__device__ inline unsigned short f2bf(float f) {
    union { float f; unsigned u; } v; v.f = f;
    unsigned r = v.u + 0x7fffu + ((v.u >> 16) & 1u);
    return (unsigned short)(r >> 16);
}

// ---------------------------------------------------------------------------
// Kernel A v3 (R11): 1x1 conv (256->64) MFMA, B-operand cast on the fly from
// fp32 w_comp, + BN + SiLU -> tpad interior.  Side jobs: build Web (1 elem per
// thread, 288*256==73728) and zero tpad's border halo (25088 elems).
// grid (wseg=3, h=48, b=2), block 256.
// ---------------------------------------------------------------------------
__global__ __launch_bounds__(256) void comp_mfma(
    const float* __restrict__ X, const float* __restrict__ w_comp,
    const float* __restrict__ w_enc,
    const float* __restrict__ g1, const float* __restrict__ b1,
    const float* __restrict__ m1, const float* __restrict__ v1,
    unsigned short* __restrict__ tpad, unsigned short* __restrict__ Web)
{
    const int wseg = blockIdx.x;
    const int h = blockIdx.y;
    const int b = blockIdx.z;
    const int tid  = threadIdx.x;

    // ---- side job 1: Web[ch][kk*64+ci] bf16 from w_enc[ch][ci][kk]
    {
        const int i = ((wseg + 3*(h + 48*b)) << 8) | tid;   // 0..73727
        const int ch = i / 576;
        const int r  = i - ch * 576;
        const int kk = r >> 6;
        const int ci = r & 63;
        const float v = (ch < 100) ? w_enc[ch * 576 + ci * 9 + kk] : 0.f;
        Web[i] = f2bf(v);
        // ---- side job 2: zero tpad border (196 px * 64 ch * 2 b)
        if (i < 25088) {
            const int bb  = i / 12544;
            const int rem = i - bb * 12544;
            const int p   = rem >> 6;
            const int chn = rem & 63;
            int rr, cc;
            if (p < 50)       { rr = 0;       cc = p;       }
            else if (p < 100) { rr = 49;      cc = p - 50;  }
            else if (p < 148) { rr = p - 99;  cc = 0;       }
            else              { rr = p - 147; cc = 49;      }
            tpad[((bb*50 + rr)*50 + cc)*64 + chn] = 0;
        }
    }

    // ---- main: comp MFMA
    const int wave = tid >> 6;
    const int l    = tid & 63;
    const int lr   = l & 15;
    const int lk   = l >> 4;
    const int w0   = wseg * 16;

    f32x4 acc = {0.f,0.f,0.f,0.f};
    const float* xb = X + (size_t)b * 589824 + h * 48 + w0 + lr;
    const float* wb = w_comp + (wave * 16 + lr) * 256;

    #pragma unroll
    for (int s = 0; s < 8; ++s) {
        const int ci0 = s * 32 + lk * 8;
        short8v a, f;
        const float4 wv0 = *(const float4*)(wb + ci0);
        const float4 wv1 = *(const float4*)(wb + ci0 + 4);
        f[0] = (short)f2bf(wv0.x); f[1] = (short)f2bf(wv0.y);
        f[2] = (short)f2bf(wv0.z); f[3] = (short)f2bf(wv0.w);
        f[4] = (short)f2bf(wv1.x); f[5] = (short)f2bf(wv1.y);
        f[6] = (short)f2bf(wv1.z); f[7] = (short)f2bf(wv1.w);
        #pragma unroll
        for (int j = 0; j < 8; ++j)
            a[j] = (short)f2bf(xb[(size_t)(ci0 + j) * 2304]);
        acc = __builtin_amdgcn_mfma_f32_16x16x32_bf16(a, f, acc, 0, 0, 0);
    }

    const int oc = wave * 16 + lr;
    const float sc = g1[oc] * rsqrtf(v1[oc] + EPS_BN);
    const float sh = b1[oc] - m1[oc] * sc;
    unsigned short* tp = tpad + ((b*50 + h + 1)*50 + 1)*64 + oc;
    #pragma unroll
    for (int r = 0; r < 4; ++r) {
        float v = fmaf(acc[r], sc, sh);
        float t = v / (1.f + __expf(-v));          // SiLU
        tp[(w0 + lk*4 + r)*64] = f2bf(t);
    }
}

// ---------------------------------------------------------------------------
// Kernel B (R4/R8): 3x3 conv (64->100) MFMA + BN + fused softmax -> Wl fp32.
// grid (wseg=3, h=48, b=2), block 256 (4 waves).
// ---------------------------------------------------------------------------
__global__ __launch_bounds__(256) void enc_sm(
    const unsigned short* __restrict__ tpad, const unsigned short* __restrict__ Web,
    const float* __restrict__ g2, const float* __restrict__ b2,
    const float* __restrict__ m2, const float* __restrict__ v2,
    float* __restrict__ Wl)
{
    const int wseg = blockIdx.x;
    const int h = blockIdx.y;
    const int b = blockIdx.z;
    const int tid  = threadIdx.x;
    const int wave = tid >> 6;
    const int l    = tid & 63;
    const int lr   = l & 15;
    const int lk   = l >> 4;
    const int w0   = wseg * 16;
    const int nt0  = wave * 2, nt1 = wave * 2 + 1;
    __shared__ float elds[16 * 116];

    f32x4 acc0 = {0.f,0.f,0.f,0.f};
    f32x4 acc1 = {0.f,0.f,0.f,0.f};

    const unsigned short* tb = tpad + (b*50 + h)*50*64;
    const unsigned short* wb0 = Web + (nt0*16 + lr)*576;
    const unsigned short* wb1 = Web + (nt1*16 + lr)*576;

    #pragma unroll 6
    for (int s = 0; s < 18; ++s) {
        const int kk = s >> 1;
        const int ky = (kk * 11) >> 5;
        const int kx = kk - ky * 3;
        const int cio = ((s & 1) << 5) + lk * 8;
        const short8v a  = *(const short8v*)(tb + (ky*50 + w0 + kx + lr)*64 + cio);
        const short8v f0 = *(const short8v*)(wb0 + kk*64 + cio);
        const short8v f1 = *(const short8v*)(wb1 + kk*64 + cio);
        acc0 = __builtin_amdgcn_mfma_f32_16x16x32_bf16(a, f0, acc0, 0, 0, 0);
        acc1 = __builtin_amdgcn_mfma_f32_16x16x32_bf16(a, f1, acc1, 0, 0, 0);
    }

    #pragma unroll
    for (int t = 0; t < 2; ++t) {
        const int nt = t ? nt1 : nt0;
        if (nt >= 7) continue;
        const int ch = nt*16 + lr;
        float sc = 0.f, sh = 0.f;
        if (ch < 100) {
            sc = g2[ch] * rsqrtf(v2[ch] + EPS_BN);
            sh = b2[ch] - m2[ch]*sc;
        }
        const f32x4 acc = t ? acc1 : acc0;
        #pragma unroll
        for (int r = 0; r < 4; ++r)
            elds[(lk*4 + r)*116 + ch] = fmaf(acc[r], sc, sh);
    }
    __syncthreads();

    if (tid < 64) {
        const int px = tid >> 2;
        const int s  = tid & 3;
        const float* ep = &elds[px*116 + s];
        float ev[25];
        float mx = -1e30f;
        #pragma unroll
        for (int k = 0; k < 25; ++k) { ev[k] = ep[4*k]; mx = fmaxf(mx, ev[k]); }
        float sum = 0.f;
        #pragma unroll
        for (int k = 0; k < 25; ++k) { ev[k] = __expf(ev[k] - mx); sum += ev[k]; }
        const float rs = 1.f / sum;
        float* wp = Wl + ((b*48 + h)*48 + w0 + px)*112 + s*28;
        #pragma unroll
        for (int k4 = 0; k4 < 6; ++k4) {
            float4 o = { ev[k4*4+0]*rs, ev[k4*4+1]*rs, ev[k4*4+2]*rs, ev[k4*4+3]*rs };
            *(float4*)(wp + k4*4) = o;
        }
        wp[24] = ev[24]*rs;
    }
}

// ---------------------------------------------------------------------------
// Kernel C v8: v6 compute + COALESCED store epilogue via LDS transpose.
// xv[25] is register-resident before the weight loop, so xl is dead after a
// barrier -> reuse it as ol[16ch][2y][96x] (12.3 KB <= 16.9 KB).  In-loop acc
// writes (4 b32 per s); final 3 fully-coalesced float4 stores per lane.
// grid (cg=16, h=48, b=2) = 1536 blocks, block 256.
// ---------------------------------------------------------------------------
__global__ __launch_bounds__(256) void carafe_v8(
    const float* __restrict__ X, const float* __restrict__ Wl,
    float* __restrict__ out)
{
    const int cg = blockIdx.x;
    const int h = blockIdx.y;
    const int b = blockIdx.z;
    __shared__ float xl[4240];    // [(ci>>2):4][r:5][cp:53][ci&3], reused as ol
    const int tid = threadIdx.x;

    // stage X: 16 ch x 5 rows x 12 f4 (cols 2..49) + border zeros
    for (int idx = tid; idx < 960; idx += 256) {
        const int ci  = idx / 60;
        const int rem = idx - ci * 60;
        const int r   = rem / 12;
        const int q   = rem - r * 12;
        const int hh  = h - 2 + r;
        float4 v = {0.f,0.f,0.f,0.f};
        if ((unsigned)hh < 48u)
            v = *(const float4*)&X[(size_t)(b*256 + cg*16 + ci)*2304 + hh*48 + q*4];
        float* base = &xl[(((ci>>2)*5 + r)*53 + 2 + q*4)*4 + (ci&3)];
        base[0]  = v.x;
        base[4]  = v.y;
        base[8]  = v.z;
        base[12] = v.w;
    }
    for (int idx = tid; idx < 320; idx += 256) {
        const int ci  = idx / 20;
        const int rem = idx - ci * 20;
        const int r   = rem / 4;
        const int e   = rem & 3;
        const int cp  = (e < 2) ? e : 48 + e;
        xl[(((ci>>2)*5 + r)*53 + cp)*4 + (ci&3)] = 0.f;
    }
    __syncthreads();

    const int c4g = tid & 3;
    const int w   = tid >> 2;    // 0..63, active < 48

    // load all taps to registers (xl dead afterwards)
    float4 xv[25];
    if (w < 48) {
        #pragma unroll
        for (int r = 0; r < 5; ++r)
            #pragma unroll
            for (int dx = 0; dx < 5; ++dx)
                xv[r*5 + dx] = *(const float4*)&xl[((c4g*5 + r)*53 + (w + dx))*4];
    }
    __syncthreads();            // all xl reads done; xl becomes ol

    float* ol = xl;             // [ch:16][y:2][x:96]
    if (w < 48) {
        const float* wb = &Wl[(size_t)((b*48 + h)*48 + w)*112];   // global, L2
        #pragma unroll
        for (int s = 0; s < 4; ++s) {
            float ax=0.f, ay=0.f, az=0.f, aw=0.f;
            #pragma unroll
            for (int k4 = 0; k4 < 6; ++k4) {
                const float4 wv = *(const float4*)&wb[s*28 + k4*4];
                const float4 p0 = xv[k4*4+0], p1 = xv[k4*4+1], p2 = xv[k4*4+2], p3 = xv[k4*4+3];
                ax = fmaf(wv.x,p0.x,fmaf(wv.y,p1.x,fmaf(wv.z,p2.x,fmaf(wv.w,p3.x,ax))));
                ay = fmaf(wv.x,p0.y,fmaf(wv.y,p1.y,fmaf(wv.z,p2.y,fmaf(wv.w,p3.y,ay))));
                az = fmaf(wv.x,p0.z,fmaf(wv.y,p1.z,fmaf(wv.z,p2.z,fmaf(wv.w,p3.z,az))));
                aw = fmaf(wv.x,p0.w,fmaf(wv.y,p1.w,fmaf(wv.z,p2.w,fmaf(wv.w,p3.w,aw))));
            }
            const float wk = wb[s*28 + 24];
            const float4 pl = xv[24];
            ax = fmaf(wk,pl.x,ax); ay = fmaf(wk,pl.y,ay);
            az = fmaf(wk,pl.z,az); aw = fmaf(wk,pl.w,aw);
            const int y = s >> 1;
            const int x = 2*w + (s & 1);
            ol[((c4g*4 + 0)*2 + y)*96 + x] = ax;
            ol[((c4g*4 + 1)*2 + y)*96 + x] = ay;
            ol[((c4g*4 + 2)*2 + y)*96 + x] = az;
            ol[((c4g*4 + 3)*2 + y)*96 + x] = aw;
        }
    }
    __syncthreads();

    // coalesced store: 768 float4 = [ch:16][y:2][xq:24], 3 per lane
    #pragma unroll
    for (int p = 0; p < 3; ++p) {
        const int fi = p*256 + tid;
        const int ch = fi / 48;
        const int rem = fi - ch*48;
        const int y  = rem / 24;
        const int xq = rem - y*24;
        const float4 v = *(const float4*)&ol[fi*4];
        *(float4*)&out[((size_t)(b*256 + cg*16 + ch)*96 + 2*h + y)*96 + xq*4] = v;
    }
}

extern "C" void kernel_launch(void* const* d_in, const int* in_sizes, int n_in,
                              void* d_out, int out_size, void* d_ws, size_t ws_size,
                              hipStream_t stream)
{
    (void)in_sizes; (void)n_in; (void)out_size; (void)ws_size;
    const float* X      = (const float*)d_in[0];
    const float* w_comp = (const float*)d_in[1];
    const float* g1     = (const float*)d_in[2];
    const float* b1     = (const float*)d_in[3];
    const float* m1     = (const float*)d_in[4];
    const float* v1     = (const float*)d_in[5];
    const float* w_enc  = (const float*)d_in[6];
    const float* g2     = (const float*)d_in[7];
    const float* b2     = (const float*)d_in[8];
    const float* m2     = (const float*)d_in[9];
    const float* v2     = (const float*)d_in[10];
    float* out = (float*)d_out;

    char* ws = (char*)d_ws;
    unsigned short* tpad = (unsigned short*)(ws + 0);        // 640000 B
    unsigned short* Web  = (unsigned short*)(ws + 640000);   // 147456 B
    float*          Wl   = (float*)(ws + 787456);            // 2064384 B

    dim3 gA(3, 48, 2);
    comp_mfma<<<gA, 256, 0, stream>>>(X, w_comp, w_enc, g1, b1, m1, v1, tpad, Web);
    dim3 gB(3, 48, 2);
    enc_sm<<<gB, 256, 0, stream>>>(tpad, Web, g2, b2, m2, v2, Wl);
    dim3 gC(16, 48, 2);
    carafe_v8<<<gC, 256, 0, stream>>>(X, Wl, out);
}

// Round 13
// 38.977 us; speedup vs baseline: 6.6674x; 1.1143x over previous
//
#include <hip/hip_runtime.h>

#define EPS_BN 1e-5f

typedef __attribute__((ext_vector_type(8))) short short8v;
typedef __attribute__((ext_vector_type(4))) float f32x4;

__device__ inline unsigned short f2bf(float f) {
    union { float f; unsigned u; } v; v.f = f;
    unsigned r = v.u + 0x7fffu + ((v.u >> 16) & 1u);
    return (unsigned short)(r >> 16);
}

// ---------------------------------------------------------------------------
// Kernel A v3 (R11/R12): 1x1 conv (256->64) MFMA + BN + SiLU -> tpad interior.
// Side jobs: build Web (1 elem/thread) and zero tpad's border halo.
// grid (wseg=3, h=48, b=2), block 256.
// ---------------------------------------------------------------------------
__global__ __launch_bounds__(256) void comp_mfma(
    const float* __restrict__ X, const float* __restrict__ w_comp,
    const float* __restrict__ w_enc,
    const float* __restrict__ g1, const float* __restrict__ b1,
    const float* __restrict__ m1, const float* __restrict__ v1,
    unsigned short* __restrict__ tpad, unsigned short* __restrict__ Web)
{
    const int wseg = blockIdx.x;
    const int h = blockIdx.y;
    const int b = blockIdx.z;
    const int tid  = threadIdx.x;

    // ---- side job 1: Web[ch][kk*64+ci] bf16 from w_enc[ch][ci][kk]
    {
        const int i = ((wseg + 3*(h + 48*b)) << 8) | tid;   // 0..73727
        const int ch = i / 576;
        const int r  = i - ch * 576;
        const int kk = r >> 6;
        const int ci = r & 63;
        const float v = (ch < 100) ? w_enc[ch * 576 + ci * 9 + kk] : 0.f;
        Web[i] = f2bf(v);
        // ---- side job 2: zero tpad border (196 px * 64 ch * 2 b)
        if (i < 25088) {
            const int bb  = i / 12544;
            const int rem = i - bb * 12544;
            const int p   = rem >> 6;
            const int chn = rem & 63;
            int rr, cc;
            if (p < 50)       { rr = 0;       cc = p;       }
            else if (p < 100) { rr = 49;      cc = p - 50;  }
            else if (p < 148) { rr = p - 99;  cc = 0;       }
            else              { rr = p - 147; cc = 49;      }
            tpad[((bb*50 + rr)*50 + cc)*64 + chn] = 0;
        }
    }

    // ---- main: comp MFMA
    const int wave = tid >> 6;
    const int l    = tid & 63;
    const int lr   = l & 15;
    const int lk   = l >> 4;
    const int w0   = wseg * 16;

    f32x4 acc = {0.f,0.f,0.f,0.f};
    const float* xb = X + (size_t)b * 589824 + h * 48 + w0 + lr;
    const float* wb = w_comp + (wave * 16 + lr) * 256;

    #pragma unroll
    for (int s = 0; s < 8; ++s) {
        const int ci0 = s * 32 + lk * 8;
        short8v a, f;
        const float4 wv0 = *(const float4*)(wb + ci0);
        const float4 wv1 = *(const float4*)(wb + ci0 + 4);
        f[0] = (short)f2bf(wv0.x); f[1] = (short)f2bf(wv0.y);
        f[2] = (short)f2bf(wv0.z); f[3] = (short)f2bf(wv0.w);
        f[4] = (short)f2bf(wv1.x); f[5] = (short)f2bf(wv1.y);
        f[6] = (short)f2bf(wv1.z); f[7] = (short)f2bf(wv1.w);
        #pragma unroll
        for (int j = 0; j < 8; ++j)
            a[j] = (short)f2bf(xb[(size_t)(ci0 + j) * 2304]);
        acc = __builtin_amdgcn_mfma_f32_16x16x32_bf16(a, f, acc, 0, 0, 0);
    }

    const int oc = wave * 16 + lr;
    const float sc = g1[oc] * rsqrtf(v1[oc] + EPS_BN);
    const float sh = b1[oc] - m1[oc] * sc;
    unsigned short* tp = tpad + ((b*50 + h + 1)*50 + 1)*64 + oc;
    #pragma unroll
    for (int r = 0; r < 4; ++r) {
        float v = fmaf(acc[r], sc, sh);
        float t = v / (1.f + __expf(-v));          // SiLU
        tp[(w0 + lk*4 + r)*64] = f2bf(t);
    }
}

// ---------------------------------------------------------------------------
// Kernel B (R4/R8): 3x3 conv (64->100) MFMA + BN + fused softmax -> Wl fp32.
// grid (wseg=3, h=48, b=2), block 256 (4 waves).
// ---------------------------------------------------------------------------
__global__ __launch_bounds__(256) void enc_sm(
    const unsigned short* __restrict__ tpad, const unsigned short* __restrict__ Web,
    const float* __restrict__ g2, const float* __restrict__ b2,
    const float* __restrict__ m2, const float* __restrict__ v2,
    float* __restrict__ Wl)
{
    const int wseg = blockIdx.x;
    const int h = blockIdx.y;
    const int b = blockIdx.z;
    const int tid  = threadIdx.x;
    const int wave = tid >> 6;
    const int l    = tid & 63;
    const int lr   = l & 15;
    const int lk   = l >> 4;
    const int w0   = wseg * 16;
    const int nt0  = wave * 2, nt1 = wave * 2 + 1;
    __shared__ float elds[16 * 116];

    f32x4 acc0 = {0.f,0.f,0.f,0.f};
    f32x4 acc1 = {0.f,0.f,0.f,0.f};

    const unsigned short* tb = tpad + (b*50 + h)*50*64;
    const unsigned short* wb0 = Web + (nt0*16 + lr)*576;
    const unsigned short* wb1 = Web + (nt1*16 + lr)*576;

    #pragma unroll 6
    for (int s = 0; s < 18; ++s) {
        const int kk = s >> 1;
        const int ky = (kk * 11) >> 5;
        const int kx = kk - ky * 3;
        const int cio = ((s & 1) << 5) + lk * 8;
        const short8v a  = *(const short8v*)(tb + (ky*50 + w0 + kx + lr)*64 + cio);
        const short8v f0 = *(const short8v*)(wb0 + kk*64 + cio);
        const short8v f1 = *(const short8v*)(wb1 + kk*64 + cio);
        acc0 = __builtin_amdgcn_mfma_f32_16x16x32_bf16(a, f0, acc0, 0, 0, 0);
        acc1 = __builtin_amdgcn_mfma_f32_16x16x32_bf16(a, f1, acc1, 0, 0, 0);
    }

    #pragma unroll
    for (int t = 0; t < 2; ++t) {
        const int nt = t ? nt1 : nt0;
        if (nt >= 7) continue;
        const int ch = nt*16 + lr;
        float sc = 0.f, sh = 0.f;
        if (ch < 100) {
            sc = g2[ch] * rsqrtf(v2[ch] + EPS_BN);
            sh = b2[ch] - m2[ch]*sc;
        }
        const f32x4 acc = t ? acc1 : acc0;
        #pragma unroll
        for (int r = 0; r < 4; ++r)
            elds[(lk*4 + r)*116 + ch] = fmaf(acc[r], sc, sh);
    }
    __syncthreads();

    if (tid < 64) {
        const int px = tid >> 2;
        const int s  = tid & 3;
        const float* ep = &elds[px*116 + s];
        float ev[25];
        float mx = -1e30f;
        #pragma unroll
        for (int k = 0; k < 25; ++k) { ev[k] = ep[4*k]; mx = fmaxf(mx, ev[k]); }
        float sum = 0.f;
        #pragma unroll
        for (int k = 0; k < 25; ++k) { ev[k] = __expf(ev[k] - mx); sum += ev[k]; }
        const float rs = 1.f / sum;
        float* wp = Wl + ((b*48 + h)*48 + w0 + px)*112 + s*28;
        #pragma unroll
        for (int k4 = 0; k4 < 6; ++k4) {
            float4 o = { ev[k4*4+0]*rs, ev[k4*4+1]*rs, ev[k4*4+2]*rs, ev[k4*4+3]*rs };
            *(float4*)(wp + k4*4) = o;
        }
        wp[24] = ev[24]*rs;
    }
}

// ---------------------------------------------------------------------------
// Kernel C v9: v8 compute/store + XCD-aware swizzle + disjoint ol (2 barriers).
// Flat grid 1536.  slot=bid&7 (XCD), k=bid>>3: h=slot+8*(k%6), cg=(k/6)%16,
// b=k/96 -> all 32 blocks sharing Wl rows of height h land on one XCD.
// LDS: xl 16.9 KB + ol 12 KB = 29.2 KB.
// ---------------------------------------------------------------------------
__global__ __launch_bounds__(256) void carafe_v9(
    const float* __restrict__ X, const float* __restrict__ Wl,
    float* __restrict__ out)
{
    const int bid  = blockIdx.x;
    const int slot = bid & 7;
    const int k    = bid >> 3;          // 0..191
    const int h    = slot + 8 * (k % 6);
    const int cg   = (k / 6) & 15;
    const int b    = k / 96;

    __shared__ float xl[4240];    // [(ci>>2):4][r:5][cp:53][ci&3]
    __shared__ float ol[3072];    // [ch:16][y:2][x:96]
    const int tid = threadIdx.x;

    // stage X: 16 ch x 5 rows x 12 f4 (cols 2..49) + border zeros
    for (int idx = tid; idx < 960; idx += 256) {
        const int ci  = idx / 60;
        const int rem = idx - ci * 60;
        const int r   = rem / 12;
        const int q   = rem - r * 12;
        const int hh  = h - 2 + r;
        float4 v = {0.f,0.f,0.f,0.f};
        if ((unsigned)hh < 48u)
            v = *(const float4*)&X[(size_t)(b*256 + cg*16 + ci)*2304 + hh*48 + q*4];
        float* base = &xl[(((ci>>2)*5 + r)*53 + 2 + q*4)*4 + (ci&3)];
        base[0]  = v.x;
        base[4]  = v.y;
        base[8]  = v.z;
        base[12] = v.w;
    }
    for (int idx = tid; idx < 320; idx += 256) {
        const int ci  = idx / 20;
        const int rem = idx - ci * 20;
        const int r   = rem / 4;
        const int e   = rem & 3;
        const int cp  = (e < 2) ? e : 48 + e;
        xl[(((ci>>2)*5 + r)*53 + cp)*4 + (ci&3)] = 0.f;
    }
    __syncthreads();

    const int c4g = tid & 3;
    const int w   = tid >> 2;    // 0..63, active < 48
    if (w < 48) {
        float4 xv[25];
        #pragma unroll
        for (int r = 0; r < 5; ++r)
            #pragma unroll
            for (int dx = 0; dx < 5; ++dx)
                xv[r*5 + dx] = *(const float4*)&xl[((c4g*5 + r)*53 + (w + dx))*4];
        const float* wb = &Wl[(size_t)((b*48 + h)*48 + w)*112];   // L2-local now
        #pragma unroll
        for (int s = 0; s < 4; ++s) {
            float ax=0.f, ay=0.f, az=0.f, aw=0.f;
            #pragma unroll
            for (int k4 = 0; k4 < 6; ++k4) {
                const float4 wv = *(const float4*)&wb[s*28 + k4*4];
                const float4 p0 = xv[k4*4+0], p1 = xv[k4*4+1], p2 = xv[k4*4+2], p3 = xv[k4*4+3];
                ax = fmaf(wv.x,p0.x,fmaf(wv.y,p1.x,fmaf(wv.z,p2.x,fmaf(wv.w,p3.x,ax))));
                ay = fmaf(wv.x,p0.y,fmaf(wv.y,p1.y,fmaf(wv.z,p2.y,fmaf(wv.w,p3.y,ay))));
                az = fmaf(wv.x,p0.z,fmaf(wv.y,p1.z,fmaf(wv.z,p2.z,fmaf(wv.w,p3.z,az))));
                aw = fmaf(wv.x,p0.w,fmaf(wv.y,p1.w,fmaf(wv.z,p2.w,fmaf(wv.w,p3.w,aw))));
            }
            const float wk = wb[s*28 + 24];
            const float4 pl = xv[24];
            ax = fmaf(wk,pl.x,ax); ay = fmaf(wk,pl.y,ay);
            az = fmaf(wk,pl.z,az); aw = fmaf(wk,pl.w,aw);
            const int y = s >> 1;
            const int x = 2*w + (s & 1);
            ol[((c4g*4 + 0)*2 + y)*96 + x] = ax;
            ol[((c4g*4 + 1)*2 + y)*96 + x] = ay;
            ol[((c4g*4 + 2)*2 + y)*96 + x] = az;
            ol[((c4g*4 + 3)*2 + y)*96 + x] = aw;
        }
    }
    __syncthreads();

    // coalesced store: 768 float4 = [ch:16][y:2][xq:24], 3 per lane
    #pragma unroll
    for (int p = 0; p < 3; ++p) {
        const int fi = p*256 + tid;
        const int ch = fi / 48;
        const int rem = fi - ch*48;
        const int y  = rem / 24;
        const int xq = rem - y*24;
        const float4 v = *(const float4*)&ol[fi*4];
        *(float4*)&out[((size_t)(b*256 + cg*16 + ch)*96 + 2*h + y)*96 + xq*4] = v;
    }
}

extern "C" void kernel_launch(void* const* d_in, const int* in_sizes, int n_in,
                              void* d_out, int out_size, void* d_ws, size_t ws_size,
                              hipStream_t stream)
{
    (void)in_sizes; (void)n_in; (void)out_size; (void)ws_size;
    const float* X      = (const float*)d_in[0];
    const float* w_comp = (const float*)d_in[1];
    const float* g1     = (const float*)d_in[2];
    const float* b1     = (const float*)d_in[3];
    const float* m1     = (const float*)d_in[4];
    const float* v1     = (const float*)d_in[5];
    const float* w_enc  = (const float*)d_in[6];
    const float* g2     = (const float*)d_in[7];
    const float* b2     = (const float*)d_in[8];
    const float* m2     = (const float*)d_in[9];
    const float* v2     = (const float*)d_in[10];
    float* out = (float*)d_out;

    char* ws = (char*)d_ws;
    unsigned short* tpad = (unsigned short*)(ws + 0);        // 640000 B
    unsigned short* Web  = (unsigned short*)(ws + 640000);   // 147456 B
    float*          Wl   = (float*)(ws + 787456);            // 2064384 B

    dim3 gA(3, 48, 2);
    comp_mfma<<<gA, 256, 0, stream>>>(X, w_comp, w_enc, g1, b1, m1, v1, tpad, Web);
    dim3 gB(3, 48, 2);
    enc_sm<<<gB, 256, 0, stream>>>(tpad, Web, g2, b2, m2, v2, Wl);
    carafe_v9<<<1536, 256, 0, stream>>>(X, Wl, out);
}

// Round 14
// 38.696 us; speedup vs baseline: 6.7160x; 1.0073x over previous
//
#include <hip/hip_runtime.h>

#define EPS_BN 1e-5f

typedef __attribute__((ext_vector_type(8))) short short8v;
typedef __attribute__((ext_vector_type(4))) float f32x4;
typedef __attribute__((ext_vector_type(4))) _Float16 h16x4;

__device__ inline unsigned short f2bf(float f) {
    union { float f; unsigned u; } v; v.f = f;
    unsigned r = v.u + 0x7fffu + ((v.u >> 16) & 1u);
    return (unsigned short)(r >> 16);
}

// ---------------------------------------------------------------------------
// Kernel A v3 (R11/R12): 1x1 conv (256->64) MFMA + BN + SiLU -> tpad interior.
// Side jobs: build Web (1 elem/thread) and zero tpad's border halo.
// grid (wseg=3, h=48, b=2), block 256.
// ---------------------------------------------------------------------------
__global__ __launch_bounds__(256) void comp_mfma(
    const float* __restrict__ X, const float* __restrict__ w_comp,
    const float* __restrict__ w_enc,
    const float* __restrict__ g1, const float* __restrict__ b1,
    const float* __restrict__ m1, const float* __restrict__ v1,
    unsigned short* __restrict__ tpad, unsigned short* __restrict__ Web)
{
    const int wseg = blockIdx.x;
    const int h = blockIdx.y;
    const int b = blockIdx.z;
    const int tid  = threadIdx.x;

    // ---- side job 1: Web[ch][kk*64+ci] bf16 from w_enc[ch][ci][kk]
    {
        const int i = ((wseg + 3*(h + 48*b)) << 8) | tid;   // 0..73727
        const int ch = i / 576;
        const int r  = i - ch * 576;
        const int kk = r >> 6;
        const int ci = r & 63;
        const float v = (ch < 100) ? w_enc[ch * 576 + ci * 9 + kk] : 0.f;
        Web[i] = f2bf(v);
        // ---- side job 2: zero tpad border (196 px * 64 ch * 2 b)
        if (i < 25088) {
            const int bb  = i / 12544;
            const int rem = i - bb * 12544;
            const int p   = rem >> 6;
            const int chn = rem & 63;
            int rr, cc;
            if (p < 50)       { rr = 0;       cc = p;       }
            else if (p < 100) { rr = 49;      cc = p - 50;  }
            else if (p < 148) { rr = p - 99;  cc = 0;       }
            else              { rr = p - 147; cc = 49;      }
            tpad[((bb*50 + rr)*50 + cc)*64 + chn] = 0;
        }
    }

    // ---- main: comp MFMA
    const int wave = tid >> 6;
    const int l    = tid & 63;
    const int lr   = l & 15;
    const int lk   = l >> 4;
    const int w0   = wseg * 16;

    f32x4 acc = {0.f,0.f,0.f,0.f};
    const float* xb = X + (size_t)b * 589824 + h * 48 + w0 + lr;
    const float* wb = w_comp + (wave * 16 + lr) * 256;

    #pragma unroll
    for (int s = 0; s < 8; ++s) {
        const int ci0 = s * 32 + lk * 8;
        short8v a, f;
        const float4 wv0 = *(const float4*)(wb + ci0);
        const float4 wv1 = *(const float4*)(wb + ci0 + 4);
        f[0] = (short)f2bf(wv0.x); f[1] = (short)f2bf(wv0.y);
        f[2] = (short)f2bf(wv0.z); f[3] = (short)f2bf(wv0.w);
        f[4] = (short)f2bf(wv1.x); f[5] = (short)f2bf(wv1.y);
        f[6] = (short)f2bf(wv1.z); f[7] = (short)f2bf(wv1.w);
        #pragma unroll
        for (int j = 0; j < 8; ++j)
            a[j] = (short)f2bf(xb[(size_t)(ci0 + j) * 2304]);
        acc = __builtin_amdgcn_mfma_f32_16x16x32_bf16(a, f, acc, 0, 0, 0);
    }

    const int oc = wave * 16 + lr;
    const float sc = g1[oc] * rsqrtf(v1[oc] + EPS_BN);
    const float sh = b1[oc] - m1[oc] * sc;
    unsigned short* tp = tpad + ((b*50 + h + 1)*50 + 1)*64 + oc;
    #pragma unroll
    for (int r = 0; r < 4; ++r) {
        float v = fmaf(acc[r], sc, sh);
        float t = v / (1.f + __expf(-v));          // SiLU
        tp[(w0 + lk*4 + r)*64] = f2bf(t);
    }
}

// ---------------------------------------------------------------------------
// Kernel B: 3x3 conv (64->100) MFMA + BN + fused softmax -> Wl fp16.
// grid (wseg=3, h=48, b=2), block 256 (4 waves).
// ---------------------------------------------------------------------------
__global__ __launch_bounds__(256) void enc_sm(
    const unsigned short* __restrict__ tpad, const unsigned short* __restrict__ Web,
    const float* __restrict__ g2, const float* __restrict__ b2,
    const float* __restrict__ m2, const float* __restrict__ v2,
    _Float16* __restrict__ Wl)
{
    const int wseg = blockIdx.x;
    const int h = blockIdx.y;
    const int b = blockIdx.z;
    const int tid  = threadIdx.x;
    const int wave = tid >> 6;
    const int l    = tid & 63;
    const int lr   = l & 15;
    const int lk   = l >> 4;
    const int w0   = wseg * 16;
    const int nt0  = wave * 2, nt1 = wave * 2 + 1;
    __shared__ float elds[16 * 116];

    f32x4 acc0 = {0.f,0.f,0.f,0.f};
    f32x4 acc1 = {0.f,0.f,0.f,0.f};

    const unsigned short* tb = tpad + (b*50 + h)*50*64;
    const unsigned short* wb0 = Web + (nt0*16 + lr)*576;
    const unsigned short* wb1 = Web + (nt1*16 + lr)*576;

    #pragma unroll 6
    for (int s = 0; s < 18; ++s) {
        const int kk = s >> 1;
        const int ky = (kk * 11) >> 5;
        const int kx = kk - ky * 3;
        const int cio = ((s & 1) << 5) + lk * 8;
        const short8v a  = *(const short8v*)(tb + (ky*50 + w0 + kx + lr)*64 + cio);
        const short8v f0 = *(const short8v*)(wb0 + kk*64 + cio);
        const short8v f1 = *(const short8v*)(wb1 + kk*64 + cio);
        acc0 = __builtin_amdgcn_mfma_f32_16x16x32_bf16(a, f0, acc0, 0, 0, 0);
        acc1 = __builtin_amdgcn_mfma_f32_16x16x32_bf16(a, f1, acc1, 0, 0, 0);
    }

    #pragma unroll
    for (int t = 0; t < 2; ++t) {
        const int nt = t ? nt1 : nt0;
        if (nt >= 7) continue;
        const int ch = nt*16 + lr;
        float sc = 0.f, sh = 0.f;
        if (ch < 100) {
            sc = g2[ch] * rsqrtf(v2[ch] + EPS_BN);
            sh = b2[ch] - m2[ch]*sc;
        }
        const f32x4 acc = t ? acc1 : acc0;
        #pragma unroll
        for (int r = 0; r < 4; ++r)
            elds[(lk*4 + r)*116 + ch] = fmaf(acc[r], sc, sh);
    }
    __syncthreads();

    if (tid < 64) {
        const int px = tid >> 2;
        const int s  = tid & 3;
        const float* ep = &elds[px*116 + s];
        float ev[25];
        float mx = -1e30f;
        #pragma unroll
        for (int k = 0; k < 25; ++k) { ev[k] = ep[4*k]; mx = fmaxf(mx, ev[k]); }
        float sum = 0.f;
        #pragma unroll
        for (int k = 0; k < 25; ++k) { ev[k] = __expf(ev[k] - mx); sum += ev[k]; }
        const float rs = 1.f / sum;
        _Float16* wp = Wl + ((b*48 + h)*48 + w0 + px)*112 + s*28;
        #pragma unroll
        for (int k4 = 0; k4 < 6; ++k4) {
            h16x4 o = { (_Float16)(ev[k4*4+0]*rs), (_Float16)(ev[k4*4+1]*rs),
                        (_Float16)(ev[k4*4+2]*rs), (_Float16)(ev[k4*4+3]*rs) };
            *(h16x4*)(wp + k4*4) = o;
        }
        wp[24] = (_Float16)(ev[24]*rs);
    }
}

// ---------------------------------------------------------------------------
// Kernel C v10: v9 + fp16 Wl reads (halves the dominant L2 read stream).
// Flat grid 1536, XCD-aware swizzle; xl 16.9 KB + ol 12 KB; 2 barriers.
// ---------------------------------------------------------------------------
__global__ __launch_bounds__(256) void carafe_v10(
    const float* __restrict__ X, const _Float16* __restrict__ Wl,
    float* __restrict__ out)
{
    const int bid  = blockIdx.x;
    const int slot = bid & 7;
    const int k    = bid >> 3;          // 0..191
    const int h    = slot + 8 * (k % 6);
    const int cg   = (k / 6) & 15;
    const int b    = k / 96;

    __shared__ float xl[4240];    // [(ci>>2):4][r:5][cp:53][ci&3]
    __shared__ float ol[3072];    // [ch:16][y:2][x:96]
    const int tid = threadIdx.x;

    // stage X: 16 ch x 5 rows x 12 f4 (cols 2..49) + border zeros
    for (int idx = tid; idx < 960; idx += 256) {
        const int ci  = idx / 60;
        const int rem = idx - ci * 60;
        const int r   = rem / 12;
        const int q   = rem - r * 12;
        const int hh  = h - 2 + r;
        float4 v = {0.f,0.f,0.f,0.f};
        if ((unsigned)hh < 48u)
            v = *(const float4*)&X[(size_t)(b*256 + cg*16 + ci)*2304 + hh*48 + q*4];
        float* base = &xl[(((ci>>2)*5 + r)*53 + 2 + q*4)*4 + (ci&3)];
        base[0]  = v.x;
        base[4]  = v.y;
        base[8]  = v.z;
        base[12] = v.w;
    }
    for (int idx = tid; idx < 320; idx += 256) {
        const int ci  = idx / 20;
        const int rem = idx - ci * 20;
        const int r   = rem / 4;
        const int e   = rem & 3;
        const int cp  = (e < 2) ? e : 48 + e;
        xl[(((ci>>2)*5 + r)*53 + cp)*4 + (ci&3)] = 0.f;
    }
    __syncthreads();

    const int c4g = tid & 3;
    const int w   = tid >> 2;    // 0..63, active < 48
    if (w < 48) {
        float4 xv[25];
        #pragma unroll
        for (int r = 0; r < 5; ++r)
            #pragma unroll
            for (int dx = 0; dx < 5; ++dx)
                xv[r*5 + dx] = *(const float4*)&xl[((c4g*5 + r)*53 + (w + dx))*4];
        const _Float16* wb = &Wl[(size_t)((b*48 + h)*48 + w)*112];   // L2-local
        #pragma unroll
        for (int s = 0; s < 4; ++s) {
            float ax=0.f, ay=0.f, az=0.f, aw=0.f;
            #pragma unroll
            for (int k4 = 0; k4 < 6; ++k4) {
                const h16x4 hv = *(const h16x4*)&wb[s*28 + k4*4];
                const float w0f = (float)hv[0], w1f = (float)hv[1];
                const float w2f = (float)hv[2], w3f = (float)hv[3];
                const float4 p0 = xv[k4*4+0], p1 = xv[k4*4+1], p2 = xv[k4*4+2], p3 = xv[k4*4+3];
                ax = fmaf(w0f,p0.x,fmaf(w1f,p1.x,fmaf(w2f,p2.x,fmaf(w3f,p3.x,ax))));
                ay = fmaf(w0f,p0.y,fmaf(w1f,p1.y,fmaf(w2f,p2.y,fmaf(w3f,p3.y,ay))));
                az = fmaf(w0f,p0.z,fmaf(w1f,p1.z,fmaf(w2f,p2.z,fmaf(w3f,p3.z,az))));
                aw = fmaf(w0f,p0.w,fmaf(w1f,p1.w,fmaf(w2f,p2.w,fmaf(w3f,p3.w,aw))));
            }
            const float wk = (float)wb[s*28 + 24];
            const float4 pl = xv[24];
            ax = fmaf(wk,pl.x,ax); ay = fmaf(wk,pl.y,ay);
            az = fmaf(wk,pl.z,az); aw = fmaf(wk,pl.w,aw);
            const int y = s >> 1;
            const int x = 2*w + (s & 1);
            ol[((c4g*4 + 0)*2 + y)*96 + x] = ax;
            ol[((c4g*4 + 1)*2 + y)*96 + x] = ay;
            ol[((c4g*4 + 2)*2 + y)*96 + x] = az;
            ol[((c4g*4 + 3)*2 + y)*96 + x] = aw;
        }
    }
    __syncthreads();

    // coalesced store: 768 float4 = [ch:16][y:2][xq:24], 3 per lane
    #pragma unroll
    for (int p = 0; p < 3; ++p) {
        const int fi = p*256 + tid;
        const int ch = fi / 48;
        const int rem = fi - ch*48;
        const int y  = rem / 24;
        const int xq = rem - y*24;
        const float4 v = *(const float4*)&ol[fi*4];
        *(float4*)&out[((size_t)(b*256 + cg*16 + ch)*96 + 2*h + y)*96 + xq*4] = v;
    }
}

extern "C" void kernel_launch(void* const* d_in, const int* in_sizes, int n_in,
                              void* d_out, int out_size, void* d_ws, size_t ws_size,
                              hipStream_t stream)
{
    (void)in_sizes; (void)n_in; (void)out_size; (void)ws_size;
    const float* X      = (const float*)d_in[0];
    const float* w_comp = (const float*)d_in[1];
    const float* g1     = (const float*)d_in[2];
    const float* b1     = (const float*)d_in[3];
    const float* m1     = (const float*)d_in[4];
    const float* v1     = (const float*)d_in[5];
    const float* w_enc  = (const float*)d_in[6];
    const float* g2     = (const float*)d_in[7];
    const float* b2     = (const float*)d_in[8];
    const float* m2     = (const float*)d_in[9];
    const float* v2     = (const float*)d_in[10];
    float* out = (float*)d_out;

    char* ws = (char*)d_ws;
    unsigned short* tpad = (unsigned short*)(ws + 0);        // 640000 B
    unsigned short* Web  = (unsigned short*)(ws + 640000);   // 147456 B
    _Float16*       Wl   = (_Float16*)(ws + 787456);         // 1032192 B

    dim3 gA(3, 48, 2);
    comp_mfma<<<gA, 256, 0, stream>>>(X, w_comp, w_enc, g1, b1, m1, v1, tpad, Web);
    dim3 gB(3, 48, 2);
    enc_sm<<<gB, 256, 0, stream>>>(tpad, Web, g2, b2, m2, v2, Wl);
    carafe_v10<<<1536, 256, 0, stream>>>(X, Wl, out);
}